// Round 7
// baseline (232.493 us; speedup 1.0000x reference)
//
#include <hip/hip_runtime.h>

// Per-row token-count histogram:
//   x: (B=1024, S=2048) int32 tokens in [0, 32128)
//   out: (B, V=32128) float32 counts
// v3: two-kernel design. Output is >=93% zeros, so:
//   K1: grid-stride f32x4 zero-fill of out (structurally identical to the
//       harness fillBufferAligned, measured 6.4 TB/s on this box => ~21 us).
//   K2: global-atomic scatter of the 2M tokens (atomicAdd f32). Freshly
//       zeroed out fits in 256MB L3, so RMWs are L3-resident; HBM writes
//       the 131.6 MB once. No LDS, no barriers, no lockstep phases.

#define VOCAB 32128
#define SEQ 2048
#define BLOCK 256

typedef float f32x4 __attribute__((ext_vector_type(4)));

__global__ __launch_bounds__(BLOCK) void zero_out_kernel(float* __restrict__ out,
                                                         int n_vec4) {
    f32x4* o4 = reinterpret_cast<f32x4*>(out);
    const f32x4 z = {0.f, 0.f, 0.f, 0.f};
    int stride = gridDim.x * BLOCK;
    for (int i = blockIdx.x * BLOCK + threadIdx.x; i < n_vec4; i += stride) {
        o4[i] = z;
    }
}

__global__ __launch_bounds__(BLOCK) void scatter_kernel(const int* __restrict__ x,
                                                        float* __restrict__ out) {
    // One block per row; 2048 tokens / 256 threads = 8 tokens/thread (2x int4).
    const int row = blockIdx.x;
    const int tid = threadIdx.x;
    const int4* xrow = reinterpret_cast<const int4*>(x + (size_t)row * SEQ);
    int4 t0 = xrow[tid];
    int4 t1 = xrow[tid + BLOCK];
    float* orow = out + (size_t)row * VOCAB;
    atomicAdd(orow + t0.x, 1.0f);
    atomicAdd(orow + t0.y, 1.0f);
    atomicAdd(orow + t0.z, 1.0f);
    atomicAdd(orow + t0.w, 1.0f);
    atomicAdd(orow + t1.x, 1.0f);
    atomicAdd(orow + t1.y, 1.0f);
    atomicAdd(orow + t1.z, 1.0f);
    atomicAdd(orow + t1.w, 1.0f);
}

extern "C" void kernel_launch(void* const* d_in, const int* in_sizes, int n_in,
                              void* d_out, int out_size, void* d_ws, size_t ws_size,
                              hipStream_t stream) {
    const int* x = (const int*)d_in[0];
    float* out = (float*)d_out;
    const int B = in_sizes[0] / SEQ;          // 1024
    const int n_vec4 = (B * VOCAB) / 4;       // 8,224,768 f32x4 (exactly divisible)

    // K1: zero the output. 2048 blocks x 256 thr, ~16 f32x4 stores/thread.
    hipLaunchKernelGGL(zero_out_kernel, dim3(2048), dim3(BLOCK), 0, stream, out, n_vec4);
    // K2: scatter-add tokens.
    hipLaunchKernelGGL(scatter_kernel, dim3(B), dim3(BLOCK), 0, stream, x, out);
}

// Round 11
// 176.232 us; speedup vs baseline: 1.3192x; 1.3192x over previous
//
#include <hip/hip_runtime.h>

// MEASUREMENT ROUND (v1-probe, GENS=4): v1's exact LDS-histogram structure
// executed 4x idempotently (zero -> scatter -> store; each generation
// rewrites the full row => identical output). Purpose: push kernel duration
// decisively above the ~82us harness poison fills so it lands in rocprof
// top-5 WITH counters under BOTH the near-roofline (K~27us -> 4K~108us) and
// structure-limited (K~50us -> 4K~200us) hypotheses. Next round reverts to
// single-pass with the informed fix.
//
//   x: (B=1024, S=2048) int32 tokens in [0, 32128)
//   out: (B, V=32128) float32 counts

#define VOCAB 32128
#define WORDS (VOCAB / 2)   // 16064 u32 words, each holds two u16 bins
#define SEQ 2048
#define BLOCK 512
#define GENS 4

__global__ __launch_bounds__(BLOCK, 4) void hist_probe_kernel(
    const int* __restrict__ x, float* __restrict__ out) {
    // Packed counts: word w holds bins 2w (low u16) and 2w+1 (high u16).
    // Max per-bin count = SEQ = 2048 < 65536 -> no carry into neighbor.
    __shared__ unsigned int cnt[WORDS];

    const int row = blockIdx.x;
    const int tid = threadIdx.x;

    // Token load once (registers persist across generations).
    // 2048 tokens / 512 threads = 4 tokens = 1x int4 per thread.
    const int4* xrow = reinterpret_cast<const int4*>(x + (size_t)row * SEQ);
    const int4 t = xrow[tid];

    uint4* c4 = reinterpret_cast<uint4*>(cnt);
    const uint2* c2 = reinterpret_cast<const uint2*>(cnt);
    float4* orow = reinterpret_cast<float4*>(out + (size_t)row * VOCAB);

    for (int g = 0; g < GENS; ++g) {
        // --- Phase 1: zero LDS (uint4 16B writes, 4016/512 ~ 8 iters) ---
        for (int i = tid; i < WORDS / 4; i += BLOCK) {
            c4[i] = make_uint4(0u, 0u, 0u, 0u);
        }
        __syncthreads();

        // --- Phase 2: scatter (packed u16 LDS atomics) ---
        atomicAdd(&cnt[t.x >> 1], 1u << ((t.x & 1) * 16));
        atomicAdd(&cnt[t.y >> 1], 1u << ((t.y & 1) * 16));
        atomicAdd(&cnt[t.z >> 1], 1u << ((t.z & 1) * 16));
        atomicAdd(&cnt[t.w >> 1], 1u << ((t.w & 1) * 16));
        __syncthreads();

        // --- Phase 3: expand u16 -> f32, coalesced float4 stores ---
        for (int i = tid; i < WORDS / 2; i += BLOCK) {
            uint2 w = c2[i];
            float4 f;
            f.x = (float)(w.x & 0xFFFFu);
            f.y = (float)(w.x >> 16);
            f.z = (float)(w.y & 0xFFFFu);
            f.w = (float)(w.y >> 16);
            orow[i] = f;
        }
        __syncthreads();   // protect cnt[] from next generation's re-zero
    }
}

extern "C" void kernel_launch(void* const* d_in, const int* in_sizes, int n_in,
                              void* d_out, int out_size, void* d_ws, size_t ws_size,
                              hipStream_t stream) {
    const int* x = (const int*)d_in[0];
    float* out = (float*)d_out;
    const int B = in_sizes[0] / SEQ;  // 1024
    hipLaunchKernelGGL(hist_probe_kernel, dim3(B), dim3(BLOCK), 0, stream, x, out);
}

// Round 19
// 139.941 us; speedup vs baseline: 1.6614x; 1.2593x over previous
//
#include <hip/hip_runtime.h>

// Per-row token-count histogram:
//   x: (B=1024, S=2048) int32 tokens in [0, 32128)
//   out: (B, V=32128) float32 counts
// v4: persistent 2-rows-per-block. Probe (R11) established: single-pass
// structure ~26us vs 20.6us write roofline (6.79 TB/s fill-measured), gap
// = startup not throughput. This version amortizes it: 512 blocks x 2 rows
// (2 resident/CU, one launch generation), next row's tokens prefetched
// during current row's store phase, NT stores (write-once output).

#define VOCAB 32128
#define WORDS (VOCAB / 2)   // 16064 u32 words, each holds two u16 bins
#define SEQ 2048
#define BLOCK 512

typedef float f32x4 __attribute__((ext_vector_type(4)));

__global__ __launch_bounds__(BLOCK, 2) void hist_rows2_kernel(
    const int* __restrict__ x, float* __restrict__ out) {
    // Packed counts: word w holds bins 2w (low u16) and 2w+1 (high u16).
    // Max per-bin count = SEQ = 2048 < 65536 -> no carry into neighbor.
    __shared__ unsigned int cnt[WORDS];

    const int row0 = blockIdx.x * 2;
    const int tid  = threadIdx.x;

    uint4* c4 = reinterpret_cast<uint4*>(cnt);
    const uint2* c2 = reinterpret_cast<const uint2*>(cnt);

    // --- Row 0 tokens: 2048 / 512 thr = one int4 per thread ---
    const int4* xrow0 = reinterpret_cast<const int4*>(x + (size_t)row0 * SEQ);
    int4 t0 = xrow0[tid];

    // --- Zero LDS (uint4 16B writes, 4016/512 ~ 8 iters) ---
    for (int i = tid; i < WORDS / 4; i += BLOCK) {
        c4[i] = make_uint4(0u, 0u, 0u, 0u);
    }
    __syncthreads();

    // --- Scatter row 0 ---
    atomicAdd(&cnt[t0.x >> 1], 1u << ((t0.x & 1) * 16));
    atomicAdd(&cnt[t0.y >> 1], 1u << ((t0.y & 1) * 16));
    atomicAdd(&cnt[t0.z >> 1], 1u << ((t0.z & 1) * 16));
    atomicAdd(&cnt[t0.w >> 1], 1u << ((t0.w & 1) * 16));
    __syncthreads();

    // --- Prefetch row 1 tokens; latency hides under row 0's store phase ---
    const int4* xrow1 = reinterpret_cast<const int4*>(x + (size_t)(row0 + 1) * SEQ);
    int4 t1 = xrow1[tid];

    // --- Store row 0 (expand u16 -> f32, NT 16B stores, 8032/512 ~ 16 it) ---
    {
        f32x4* orow = reinterpret_cast<f32x4*>(out + (size_t)row0 * VOCAB);
        for (int i = tid; i < WORDS / 2; i += BLOCK) {
            uint2 w = c2[i];
            f32x4 f;
            f.x = (float)(w.x & 0xFFFFu);
            f.y = (float)(w.x >> 16);
            f.z = (float)(w.y & 0xFFFFu);
            f.w = (float)(w.y >> 16);
            __builtin_nontemporal_store(f, orow + i);
        }
    }
    __syncthreads();   // cnt[] fully read before re-zero

    // --- Zero LDS for row 1 ---
    for (int i = tid; i < WORDS / 4; i += BLOCK) {
        c4[i] = make_uint4(0u, 0u, 0u, 0u);
    }
    __syncthreads();

    // --- Scatter row 1 ---
    atomicAdd(&cnt[t1.x >> 1], 1u << ((t1.x & 1) * 16));
    atomicAdd(&cnt[t1.y >> 1], 1u << ((t1.y & 1) * 16));
    atomicAdd(&cnt[t1.z >> 1], 1u << ((t1.z & 1) * 16));
    atomicAdd(&cnt[t1.w >> 1], 1u << ((t1.w & 1) * 16));
    __syncthreads();

    // --- Store row 1 ---
    {
        f32x4* orow = reinterpret_cast<f32x4*>(out + (size_t)(row0 + 1) * VOCAB);
        for (int i = tid; i < WORDS / 2; i += BLOCK) {
            uint2 w = c2[i];
            f32x4 f;
            f.x = (float)(w.x & 0xFFFFu);
            f.y = (float)(w.x >> 16);
            f.z = (float)(w.y & 0xFFFFu);
            f.w = (float)(w.y >> 16);
            __builtin_nontemporal_store(f, orow + i);
        }
    }
}

extern "C" void kernel_launch(void* const* d_in, const int* in_sizes, int n_in,
                              void* d_out, int out_size, void* d_ws, size_t ws_size,
                              hipStream_t stream) {
    const int* x = (const int*)d_in[0];
    float* out = (float*)d_out;
    const int B = in_sizes[0] / SEQ;  // 1024
    hipLaunchKernelGGL(hist_rows2_kernel, dim3(B / 2), dim3(BLOCK), 0, stream, x, out);
}